// Round 3
// baseline (574.617 us; speedup 1.0000x reference)
//
#include <hip/hip_runtime.h>
#include <hip/hip_bf16.h>

// Problem constants
#define BB 4096
#define NNA 11
#define BN (BB*NNA)      // 45056

// ws float offsets (f32 scratch unless noted)
#define OFF_WEFF   0         // [4][256]
#define OFF_BIASL  1024      // [12][256]
#define OFF_WBIG   4096      // [48][256]
#define OFF_BIAS2  16384     // (unused; bias2 inlined into k_p3)
#define OFF_WALL   16640     // [48][256]
#define OFF_BIASN  28928     // (unused; biasN inlined into k_p4/k_front)
#define OFF_WG1F   31744     // [48][1152]
#define OFF_BIASG1 87040     // [11][1152]
#define OFF_WG2    99712     // bf16 WT[128][1536] (transposed tail weight), 98304 floats
#define OFF_WQT    198656    // bf16 WQT[64][128], 4096 floats
#define OFF_P2T    202752    // [12][256] per-l bias2 partials
#define OFF_P3T    205824    // [256] bias2@Wfc3_top
#define OFF_MIX    296320    // [4096][242]  attn(121)|A(121)
#define OFF_INTER  1287552   // bf16 region start (float-offset): inter[BN][256], hyp[BN][256]

typedef short bh8 __attribute__((ext_vector_type(8)));   // 8 bf16 (4 VGPRs) MFMA A/B frag
typedef float fx4 __attribute__((ext_vector_type(4)));   // MFMA C/D frag

__device__ __forceinline__ short f2bs(float v) { __hip_bfloat16 h = __float2bfloat16(v); return *(short*)&h; }

// ---------- Prologue: weight folding (f32, K-split mini-GEMMs) ----------

// grid 4: C[16][256] = A[16][512] @ W_pos[512][256]
__global__ __launch_bounds__(256) void k_p1(const float* W_in, const float* b_in,
                                            const float* W_pos, const float* b_pos,
                                            float* ws) {
  __shared__ float A[16*512];
  __shared__ float red[4*16*64];
  int t = threadIdx.x, cb = blockIdx.x;
  int ks = t >> 6, c = t & 63, col = cb*64 + c;
  float coef = -logf(10000.f) / 256.f;
  for (int i = t; i < 16*512; i += 256) {
    int row = i >> 9, kk = i & 511;
    float v;
    if (row < 4) v = (kk < 256) ? W_in[row*256 + kk] : 0.f;
    else if (kk < 256) v = b_in[kk];
    else {
      int ii = (kk - 256) >> 1;
      float dv = expf(coef * (float)(2*ii));
      float ang = (float)(row - 4) * dv;
      v = (kk & 1) ? cosf(ang) : sinf(ang);
    }
    A[i] = v;
  }
  __syncthreads();
  float acc[16];
  #pragma unroll
  for (int r = 0; r < 16; ++r) acc[r] = 0.f;
  #pragma unroll 4
  for (int j = 0; j < 128; ++j) {
    int jj = ks*128 + j;
    float b = W_pos[(size_t)jj*256 + col];
    #pragma unroll
    for (int r = 0; r < 16; ++r) acc[r] += A[r*512 + jj] * b;
  }
  #pragma unroll
  for (int r = 0; r < 16; ++r) red[(ks*16 + r)*64 + c] = acc[r];
  __syncthreads();
  for (int i = t; i < 16*64; i += 256) {
    int row = i >> 6, cc = i & 63;
    float s = red[row*64+cc] + red[(16+row)*64+cc] + red[(32+row)*64+cc] + red[(48+row)*64+cc];
    int gcol = cb*64 + cc;
    if (row < 4) ws[OFF_WEFF + row*256 + gcol] = s;
    else         ws[OFF_BIASL + (row-4)*256 + gcol] = s + b_pos[gcol];
  }
}

// grid (4,12): per l, C[5][256] = A_l[5][256] @ W_fc2_l ; rows 0..3 -> W_big[l*4+c], row 4 -> P2T[l]
__global__ __launch_bounds__(256) void k_p2(const float* W_fc2, float* ws) {
  __shared__ float A[5*256];
  __shared__ float red[4*5*64];
  int t = threadIdx.x, cb = blockIdx.x, l = blockIdx.y;
  int ks = t >> 6, c = t & 63, col = cb*64 + c;
  for (int i = t; i < 5*256; i += 256) {
    int row = i >> 8, kk = i & 255;
    A[i] = (row < 4) ? ws[OFF_WEFF + row*256 + kk] : ws[OFF_BIASL + l*256 + kk];
  }
  __syncthreads();
  float acc[5] = {0.f, 0.f, 0.f, 0.f, 0.f};
  #pragma unroll 4
  for (int j = 0; j < 64; ++j) {
    int jj = ks*64 + j;
    float b = W_fc2[(size_t)(l*256 + jj)*256 + col];
    #pragma unroll
    for (int r = 0; r < 5; ++r) acc[r] += A[r*256 + jj] * b;
  }
  #pragma unroll
  for (int r = 0; r < 5; ++r) red[(ks*5 + r)*64 + c] = acc[r];
  __syncthreads();
  for (int i = t; i < 5*64; i += 256) {
    int row = i / 64, cc = i % 64;
    float s = red[row*64+cc] + red[(5+row)*64+cc] + red[(10+row)*64+cc] + red[(15+row)*64+cc];
    int gcol = cb*64 + cc;
    if (row < 4) ws[OFF_WBIG + (l*4 + row)*256 + gcol] = s;
    else         ws[OFF_P2T + l*256 + gcol] = s;
  }
}

// grid (4,7): C[49][256] = A[49][256] @ W_fc3_top ; rows 0..47 -> W_all, row 48 -> P3T
// bias2 (= b_fc2 + sum_l P2T[l]) is inlined here (replaces old k_p2b launch)
__global__ __launch_bounds__(256) void k_p3(const float* W_fc3, const float* b_fc2, float* ws) {
  __shared__ float A[7*256];
  __shared__ float red[4*7*64];
  int t = threadIdx.x, cb = blockIdx.x, rg = blockIdx.y;
  int ks = t >> 6, c = t & 63, col = cb*64 + c;
  for (int i = t; i < 7*256; i += 256) {
    int row = i >> 8, kk = i & 255, gr = rg*7 + row;
    float v;
    if (gr < 48) v = ws[OFF_WBIG + gr*256 + kk];
    else {
      v = b_fc2[kk];
      #pragma unroll
      for (int l = 0; l < 12; ++l) v += ws[OFF_P2T + l*256 + kk];
    }
    A[i] = v;
  }
  __syncthreads();
  float acc[7] = {0.f,0.f,0.f,0.f,0.f,0.f,0.f};
  #pragma unroll 4
  for (int j = 0; j < 64; ++j) {
    int jj = ks*64 + j;
    float b = W_fc3[(size_t)jj*256 + col];
    #pragma unroll
    for (int r = 0; r < 7; ++r) acc[r] += A[r*256 + jj] * b;
  }
  #pragma unroll
  for (int r = 0; r < 7; ++r) red[(ks*7 + r)*64 + c] = acc[r];
  __syncthreads();
  for (int i = t; i < 7*64; i += 256) {
    int row = i / 64, cc = i % 64, gr = rg*7 + row;
    float s = red[row*64+cc] + red[(7+row)*64+cc] + red[(14+row)*64+cc] + red[(21+row)*64+cc];
    int gcol = cb*64 + cc;
    if (gr < 48)       ws[OFF_WALL + gr*256 + gcol] = s;
    else if (gr == 48) ws[OFF_P3T + gcol] = s;
  }
}

// Wg1 column map: [Wm_top|Wm_bot|Wh_top|Wh_bot|Wo_ftraj] (1152 cols)
__device__ __forceinline__ float wg1_elem(int j, int col, const float* W_msg,
                                          const float* W_hyp, const float* W_out) {
  if (col < 256)       return W_msg[j*256 + col];
  else if (col < 512)  return W_msg[(256+j)*256 + (col-256)];
  else if (col < 768)  return W_hyp[j*256 + (col-512)];
  else if (col < 1024) return W_hyp[(256+j)*256 + (col-768)];
  else                 return W_out[(960+j)*128 + (col-1024)];
}

// grid (18,8): C[59][1152] = A[59][256] @ Wg1 ; rows 0..47 -> Wg1f, 48..58 -> biasg1 (+b_msg/b_hyp)
// biasN (= P3T + b_fc3 + W_fc3[256+n]) inlined here (replaces old k_p3b launch)
__global__ __launch_bounds__(256) void k_p4(const float* W_msg, const float* b_msg,
                                            const float* W_hyp, const float* b_hyp,
                                            const float* W_out, const float* W_fc3,
                                            const float* b_fc3, float* ws) {
  __shared__ float A[8*256];
  __shared__ float red[4*8*64];
  int t = threadIdx.x, cb = blockIdx.x, rg = blockIdx.y;
  int ks = t >> 6, c = t & 63, col = cb*64 + c;
  for (int i = t; i < 8*256; i += 256) {
    int row = i >> 8, kk = i & 255, gr = rg*8 + row;
    float v;
    if (gr < 48)      v = ws[OFF_WALL + gr*256 + kk];
    else if (gr < 59) v = ws[OFF_P3T + kk] + b_fc3[kk] + W_fc3[(size_t)(256 + gr - 48)*256 + kk];
    else              v = 0.f;
    A[i] = v;
  }
  __syncthreads();
  float acc[8];
  #pragma unroll
  for (int r = 0; r < 8; ++r) acc[r] = 0.f;
  #pragma unroll 4
  for (int j = 0; j < 64; ++j) {
    int jj = ks*64 + j;
    float b = wg1_elem(jj, col, W_msg, W_hyp, W_out);
    #pragma unroll
    for (int r = 0; r < 8; ++r) acc[r] += A[r*256 + jj] * b;
  }
  #pragma unroll
  for (int r = 0; r < 8; ++r) red[(ks*8 + r)*64 + c] = acc[r];
  __syncthreads();
  for (int i = t; i < 8*64; i += 256) {
    int row = i >> 6, cc = i & 63, gr = rg*8 + row;
    float s = red[row*64+cc] + red[(8+row)*64+cc] + red[(16+row)*64+cc] + red[(24+row)*64+cc];
    int gcol = cb*64 + cc;
    if (gr < 48) {
      ws[OFF_WG1F + gr*1152 + gcol] = s;
    } else if (gr < 59) {
      if (gcol < 256) s += b_msg[gcol];
      else if (gcol >= 512 && gcol < 768) s += b_hyp[gcol-512];
      ws[OFF_BIASG1 + (gr-48)*1152 + gcol] = s;
    }
  }
}

// grid 1600, block 128: blocks 0..1535: WT[c][r] (bf16, transposed) for tail GEMM;
// blocks 1536..1599: WQT[n][k] = bf16(W_qz[k][n])  (replaces old k_p6 launch)
__global__ __launch_bounds__(128) void k_p5(const float* W_line, const float* W_out,
                                            const float* W_qz, float* ws) {
  int t = threadIdx.x;
  if (blockIdx.x >= 1536) {
    int i = (blockIdx.x - 1536)*128 + t;   // 0..8191
    int n = i >> 7, k = i & 127;
    short* WQs = (short*)(ws + OFF_WQT);
    WQs[n*128 + k] = f2bs(W_qz[k*64 + n]);
    return;
  }
  int c = t, r = blockIdx.x;
  float v;
  if (r < 960)       v = W_out[r*128 + c];
  else if (r < 1216) v = W_out[(r+256)*128 + c];
  else if (r < 1472) {
    int dd = r - 1216;
    float s = 0.f;
    for (int j = 0; j < 64; ++j)
      s += W_line[dd*64 + j] * W_out[(1472+j)*128 + c];
    v = s;
  } else if (r < 1520) {
    v = ws[OFF_WG1F + (r-1472)*1152 + 1024 + c];
  } else v = 0.f;
  short* WTs = (short*)(ws + OFF_WG2);
  WTs[(size_t)c*1536 + r] = f2bs(v);
}

// ---------- Front: ftraj GEMM (K=48) + per-scene corr -> attn/A ----------
__global__ __launch_bounds__(256) void k_front(const float* inputs, const float* W_fc3,
                                               const float* b_fc3, float* ws) {
  __shared__ float XT[48*44];
  __shared__ float F[44*260];
  __shared__ float C[4*121];
  int t = threadIdx.x;
  int R0 = blockIdx.x * 44;
  for (int i = t; i < 44*48; i += 256) {
    int r = i / 48, k = i - r*48;
    XT[k*44 + r] = inputs[(size_t)(R0+r)*48 + k];
  }
  __syncthreads();
  { // ftraj = X48 @ W_all + bias_n (biasN inlined: P3T + b_fc3 + W_fc3 row)
    int d = t;
    float acc[44];
    float base = ws[OFF_P3T + d] + b_fc3[d];
    #pragma unroll
    for (int r = 0; r < 44; ++r) acc[r] = base + W_fc3[(size_t)(256 + (r % 11))*256 + d];
    for (int k = 0; k < 48; ++k) {
      float w = ws[OFF_WALL + k*256 + d];
      #pragma unroll
      for (int j = 0; j < 11; ++j) {
        float4 xv = *(const float4*)&XT[k*44 + 4*j];
        acc[4*j+0] += xv.x*w; acc[4*j+1] += xv.y*w;
        acc[4*j+2] += xv.z*w; acc[4*j+3] += xv.w*w;
      }
    }
    #pragma unroll
    for (int r = 0; r < 44; ++r) F[r*260 + d] = acc[r];
  }
  __syncthreads();
  int w = t >> 6, lane = t & 63;
  { // gram
    const float4* F4 = (const float4*)F;
    for (int p = lane; p < 66; p += 64) {
      int n = 0, pp = p;
      while (pp >= 11 - n) { pp -= 11 - n; ++n; }
      int m = n + pp;
      int ra = (w*11 + n) * 65, rb2 = (w*11 + m) * 65;
      float s = 0.f;
      #pragma unroll 4
      for (int j = 0; j < 64; ++j) {
        float4 a = F4[ra + j], b = F4[rb2 + j];
        s += a.x*b.x + a.y*b.y + a.z*b.z + a.w*b.w;
      }
      C[w*121 + n*11 + m] = s;
      C[w*121 + m*11 + n] = s;
    }
  }
  __syncthreads();
  { // attn + A
    float* Cw = C + w*121;
    float rn[11];
    #pragma unroll
    for (int n = 0; n < 11; ++n) rn[n] = 1.f / sqrtf(Cw[n*11+n]);
    float a = 1e30f;
    for (int n = 0; n < 11; ++n)
      for (int m = 0; m < 11; ++m)
        a = fminf(a, Cw[n*11+m] * rn[n] * rn[m]);
    float thr = (a < 0.4f) ? 0.4f : (((a > 0.4f) && (a < 0.6f)) ? a + 0.1f : a + 0.03f);
    int scene = blockIdx.x*4 + w;
    float* mixb = ws + OFF_MIX + (size_t)scene*242;
    if (lane < 11) {
      int n = lane;
      float mx = -1e30f;
      #pragma unroll
      for (int m = 0; m < 11; ++m) mx = fmaxf(mx, Cw[n*11+m]);
      mx *= (1.f/16.f);
      float e[11], ssum = 0.f;
      #pragma unroll
      for (int m = 0; m < 11; ++m) { e[m] = expf(Cw[n*11+m]*(1.f/16.f) - mx); ssum += e[m]; }
      float inv = 1.f / ssum;
      #pragma unroll
      for (int m = 0; m < 11; ++m) mixb[n*11+m] = e[m]*inv;
      float keep[11], cnt = 0.f;
      #pragma unroll
      for (int m = 0; m < 11; ++m) {
        float q = Cw[n*11+m] * rn[n] * rn[m];
        keep[m] = (q >= thr) ? 1.f : 0.f; cnt += keep[m];
      }
      float sc = 1.f / fmaxf(cnt, 1.f);
      #pragma unroll
      for (int m = 0; m < 11; ++m) mixb[121 + n*11 + m] = keep[m]*sc;
    }
  }
}

// ---------- Mix: P = X48 @ Wg1f (+bias), register attn/A mixing, relu -> inter/hyp (bf16) ----------
__global__ __launch_bounds__(256) void k_mix(const float* inputs, float* ws,
                                             __hip_bfloat16* outI, __hip_bfloat16* outH) {
  __shared__ float XT[48*24];
  __shared__ float MW[2*121];
  int t = threadIdx.x;
  int s0 = blockIdx.x * 2;
  int R0 = s0 * 11;
  int gy = blockIdx.y;
  __hip_bfloat16* dst = gy ? outH : outI;
  for (int i = t; i < 22*48; i += 256) {
    int r = i / 48, k = i - r*48;
    XT[k*24 + r] = inputs[(size_t)(R0+r)*48 + k];
  }
  for (int i = t; i < 96; i += 256) { int k = i >> 1, r = 22 + (i & 1); XT[k*24+r] = 0.f; }
  for (int i = t; i < 242; i += 256) {
    int s = i / 121, j = i - s*121;
    MW[i] = ws[OFF_MIX + (size_t)(s0+s)*242 + gy*121 + j];
  }
  __syncthreads();
  int gc = gy*512 + t;
  float accT[24], accB[24];
  #pragma unroll
  for (int r = 0; r < 24; ++r) {
    if (r < 22) {
      accT[r] = ws[OFF_BIASG1 + (r % 11)*1152 + gc];
      accB[r] = ws[OFF_BIASG1 + (r % 11)*1152 + gc + 256];
    } else { accT[r] = 0.f; accB[r] = 0.f; }
  }
  for (int k = 0; k < 48; ++k) {
    float wt = ws[OFF_WG1F + k*1152 + gc];
    float wb = ws[OFF_WG1F + k*1152 + gc + 256];
    #pragma unroll
    for (int j = 0; j < 6; ++j) {
      float4 xv = *(const float4*)&XT[k*24 + 4*j];
      accT[4*j+0] += xv.x*wt; accT[4*j+1] += xv.y*wt; accT[4*j+2] += xv.z*wt; accT[4*j+3] += xv.w*wt;
      accB[4*j+0] += xv.x*wb; accB[4*j+1] += xv.y*wb; accB[4*j+2] += xv.z*wb; accB[4*j+3] += xv.w*wb;
    }
  }
  #pragma unroll
  for (int s = 0; s < 2; ++s)
    #pragma unroll
    for (int n = 0; n < 11; ++n) {
      float v = accT[s*11+n];
      #pragma unroll
      for (int m = 0; m < 11; ++m)
        v += MW[s*121 + n*11 + m] * accB[s*11+m];
      v = fmaxf(v, 0.f);
      dst[(size_t)(R0 + s*11 + n)*256 + t] = __float2bfloat16(v);
    }
}

// ---------- Tail: bf16 MFMA GEMM, barrier-free direct-load streaming ----------
// grid 704, block 256 (4 waves). Tile M=64 x N=128, K=1536 in 24 chunks of 64.
// NO LDS in the main loop: A frags load straight from global into registers
// (past/x48 f32 -> cvt, inter/hyp bf16 direct); B frags load straight from WT
// (384 KB, L2-resident per XCD). No __syncthreads in the K-loop -> no vmcnt(0)
// drains; the compiler pipelines plain register loads with counted waitcnts and
// 16 waves/CU provide TLP. A raw s_barrier per chunk (rendezvous only, no drain,
// no correctness dependence) bounds wave drift so the block's shared A/B cache
// lines stay L2-hot. Per-lane frag gather is identical to the old LDS reads ->
// bit-identical output. LDS = 34 KB epilogue only; VGPR capped for 4 waves/EU.
#define HS_OFF 0
#define WQ_OFF 8704
__global__ __launch_bounds__(256, 4) void k_g2(const float* past, const float* inputs,
                                            const float* b_out, const float* b_qz,
                                            const __hip_bfloat16* interI, const __hip_bfloat16* hypI,
                                            float* ws, float* out) {
  __shared__ short LDS[17408];   // 34 KB (epilogue only) -> 4 blocks/CU
  int t = threadIdx.x;
  int R0 = blockIdx.x * 64;
  int w = t >> 6, lane = t & 63, quad = lane >> 4, l16 = lane & 15;
  const short* WTs = (const short*)(ws + OFF_WG2);
  const short* WQs = (const short*)(ws + OFF_WQT);
  const short* intS = (const short*)interI;
  const short* hypS = (const short*)hypI;

  // acc init: b_out[col] + biasg1_tail[row%11][col]
  fx4 acc[4][2];
  #pragma unroll
  for (int mt = 0; mt < 4; ++mt)
    #pragma unroll
    for (int reg = 0; reg < 4; ++reg) {
      int nidx = (R0 + mt*16 + quad*4 + reg) % 11;
      #pragma unroll
      for (int nt = 0; nt < 2; ++nt) {
        int col = w*32 + nt*16 + l16;
        acc[mt][nt][reg] = b_out[col] + ws[OFF_BIASG1 + nidx*1152 + 1024 + col];
      }
    }

  // B row pointers (WT[col][k], k contiguous): this wave's two output cols per lane
  const short* bp0 = WTs + (size_t)(w*32 + l16)*1536;
  const short* bp1 = WTs + (size_t)(w*32 + 16 + l16)*1536;
  // A row pointers per mt
  const float* pr[4];
  const short* ir[4];
  const short* hr[4];
  #pragma unroll
  for (int mt = 0; mt < 4; ++mt) {
    int row = R0 + mt*16 + l16;
    pr[mt] = past + (size_t)row*960;
    ir[mt] = intS + (size_t)row*256;
    hr[mt] = hypS + (size_t)row*256;
  }

  // ---- K-loop, split by A-source type (branch-free bodies) ----
  // past: chunks 0..14 (virtual k 0..959, f32)
  for (int ch = 0; ch < 15; ++ch) {
    #pragma unroll
    for (int ks = 0; ks < 2; ++ks) {
      int kq = ch*64 + ks*32 + quad*8;
      bh8 b0 = *(const bh8*)(bp0 + kq);
      bh8 b1 = *(const bh8*)(bp1 + kq);
      #pragma unroll
      for (int mt = 0; mt < 4; ++mt) {
        const float4* ap = (const float4*)(pr[mt] + kq);
        float4 v0 = ap[0], v1 = ap[1];
        bh8 af;
        af[0]=f2bs(v0.x); af[1]=f2bs(v0.y); af[2]=f2bs(v0.z); af[3]=f2bs(v0.w);
        af[4]=f2bs(v1.x); af[5]=f2bs(v1.y); af[6]=f2bs(v1.z); af[7]=f2bs(v1.w);
        acc[mt][0] = __builtin_amdgcn_mfma_f32_16x16x32_bf16(af, b0, acc[mt][0], 0, 0, 0);
        acc[mt][1] = __builtin_amdgcn_mfma_f32_16x16x32_bf16(af, b1, acc[mt][1], 0, 0, 0);
      }
    }
    __builtin_amdgcn_s_barrier();   // rendezvous only: bounds wave drift, no waitcnt drain
  }
  // inter: chunks 15..18 (virtual k 960..1215, bf16)
  for (int ch = 0; ch < 4; ++ch) {
    #pragma unroll
    for (int ks = 0; ks < 2; ++ks) {
      int kq = ch*64 + ks*32 + quad*8;        // 0..255 within inter
      bh8 b0 = *(const bh8*)(bp0 + 960 + kq);
      bh8 b1 = *(const bh8*)(bp1 + 960 + kq);
      #pragma unroll
      for (int mt = 0; mt < 4; ++mt) {
        bh8 af = *(const bh8*)(ir[mt] + kq);
        acc[mt][0] = __builtin_amdgcn_mfma_f32_16x16x32_bf16(af, b0, acc[mt][0], 0, 0, 0);
        acc[mt][1] = __builtin_amdgcn_mfma_f32_16x16x32_bf16(af, b1, acc[mt][1], 0, 0, 0);
      }
    }
    __builtin_amdgcn_s_barrier();
  }
  // hyp: chunks 19..22 (virtual k 1216..1471, bf16)
  for (int ch = 0; ch < 4; ++ch) {
    #pragma unroll
    for (int ks = 0; ks < 2; ++ks) {
      int kq = ch*64 + ks*32 + quad*8;        // 0..255 within hyp
      bh8 b0 = *(const bh8*)(bp0 + 1216 + kq);
      bh8 b1 = *(const bh8*)(bp1 + 1216 + kq);
      #pragma unroll
      for (int mt = 0; mt < 4; ++mt) {
        bh8 af = *(const bh8*)(hr[mt] + kq);
        acc[mt][0] = __builtin_amdgcn_mfma_f32_16x16x32_bf16(af, b0, acc[mt][0], 0, 0, 0);
        acc[mt][1] = __builtin_amdgcn_mfma_f32_16x16x32_bf16(af, b1, acc[mt][1], 0, 0, 0);
      }
    }
    __builtin_amdgcn_s_barrier();
  }
  // x48: chunk 23 (virtual k 1472..1535; cols 48..63 are zero)
  {
    #pragma unroll
    for (int ks = 0; ks < 2; ++ks) {
      int kq = ks*32 + quad*8;
      bh8 b0 = *(const bh8*)(bp0 + 1472 + kq);
      bh8 b1 = *(const bh8*)(bp1 + 1472 + kq);
      #pragma unroll
      for (int mt = 0; mt < 4; ++mt) {
        bh8 af = {0,0,0,0,0,0,0,0};
        if (kq < 48) {
          const float4* ap = (const float4*)(inputs + (size_t)(R0 + mt*16 + l16)*48 + kq);
          float4 v0 = ap[0], v1 = ap[1];
          af[0]=f2bs(v0.x); af[1]=f2bs(v0.y); af[2]=f2bs(v0.z); af[3]=f2bs(v0.w);
          af[4]=f2bs(v1.x); af[5]=f2bs(v1.y); af[6]=f2bs(v1.z); af[7]=f2bs(v1.w);
        }
        acc[mt][0] = __builtin_amdgcn_mfma_f32_16x16x32_bf16(af, b0, acc[mt][0], 0, 0, 0);
        acc[mt][1] = __builtin_amdgcn_mfma_f32_16x16x32_bf16(af, b1, acc[mt][1], 0, 0, 0);
      }
    }
  }

  // hs = relu(acc) as bf16 into LDS (C layout: row = quad*4+reg, col = l16 within tiles)
  #pragma unroll
  for (int mt = 0; mt < 4; ++mt)
    #pragma unroll
    for (int nt = 0; nt < 2; ++nt)
      #pragma unroll
      for (int reg = 0; reg < 4; ++reg)
        LDS[HS_OFF + (mt*16 + quad*4 + reg)*136 + w*32 + nt*16 + l16] = f2bs(fmaxf(acc[mt][nt][reg], 0.f));
  { // stage WQT (64 n x 128 k)
    int n = t >> 2, kh = (t & 3) * 32;
    const short* s = WQs + n*128 + kh;
    #pragma unroll
    for (int q = 0; q < 4; ++q)
      *(bh8*)&LDS[WQ_OFF + n*136 + kh + q*8] = *(const bh8*)&s[q*8];
  }
  __syncthreads();
  // out = h @ W_qz + b_qz : M=64, N=64 (16/wave), K=128
  fx4 acc2[4];
  {
    float bq = b_qz[w*16 + l16];
    #pragma unroll
    for (int mt = 0; mt < 4; ++mt) { acc2[mt][0]=bq; acc2[mt][1]=bq; acc2[mt][2]=bq; acc2[mt][3]=bq; }
  }
  #pragma unroll
  for (int ks = 0; ks < 4; ++ks) {
    int kk = ks*32 + quad*8;
    bh8 bb = *(const bh8*)&LDS[WQ_OFF + (w*16 + l16)*136 + kk];
    #pragma unroll
    for (int mt = 0; mt < 4; ++mt) {
      bh8 aa = *(const bh8*)&LDS[HS_OFF + (mt*16 + l16)*136 + kk];
      acc2[mt] = __builtin_amdgcn_mfma_f32_16x16x32_bf16(aa, bb, acc2[mt], 0, 0, 0);
    }
  }
  #pragma unroll
  for (int mt = 0; mt < 4; ++mt)
    #pragma unroll
    for (int reg = 0; reg < 4; ++reg)
      out[(size_t)(R0 + mt*16 + quad*4 + reg)*64 + w*16 + l16] = acc2[mt][reg];
}

extern "C" void kernel_launch(void* const* d_in, const int* in_sizes, int n_in,
                              void* d_out, int out_size, void* d_ws, size_t ws_size,
                              hipStream_t stream) {
  const float* inputs = (const float*)d_in[0];
  const float* past   = (const float*)d_in[1];
  const float* W_in   = (const float*)d_in[2];
  const float* b_in   = (const float*)d_in[3];
  const float* W_pos  = (const float*)d_in[4];
  const float* b_pos  = (const float*)d_in[5];
  const float* W_fc2  = (const float*)d_in[6];
  const float* b_fc2  = (const float*)d_in[7];
  const float* W_fc3  = (const float*)d_in[8];
  const float* b_fc3  = (const float*)d_in[9];
  const float* W_msg  = (const float*)d_in[10];
  const float* b_msg  = (const float*)d_in[11];
  const float* W_hyp  = (const float*)d_in[12];
  const float* b_hyp  = (const float*)d_in[13];
  const float* W_line = (const float*)d_in[14];
  const float* W_out  = (const float*)d_in[15];
  const float* b_out  = (const float*)d_in[16];
  const float* W_qz   = (const float*)d_in[17];
  const float* b_qz   = (const float*)d_in[18];
  float* ws = (float*)d_ws;
  __hip_bfloat16* interI = (__hip_bfloat16*)(ws + OFF_INTER);
  __hip_bfloat16* hypI   = interI + (size_t)BN*256;
  float* outp   = (float*)d_out;

  hipLaunchKernelGGL(k_p1,  dim3(4),      dim3(256), 0, stream, W_in, b_in, W_pos, b_pos, ws);
  hipLaunchKernelGGL(k_p2,  dim3(4, 12),  dim3(256), 0, stream, W_fc2, ws);
  hipLaunchKernelGGL(k_p3,  dim3(4, 7),   dim3(256), 0, stream, W_fc3, b_fc2, ws);
  hipLaunchKernelGGL(k_p4,  dim3(18, 8),  dim3(256), 0, stream, W_msg, b_msg, W_hyp, b_hyp, W_out, W_fc3, b_fc3, ws);
  hipLaunchKernelGGL(k_p5,  dim3(1600),   dim3(128), 0, stream, W_line, W_out, W_qz, ws);
  hipLaunchKernelGGL(k_front, dim3(1024), dim3(256), 0, stream, inputs, W_fc3, b_fc3, ws);
  hipLaunchKernelGGL(k_mix, dim3(2048, 2), dim3(256), 0, stream, inputs, ws, interI, hypI);
  hipLaunchKernelGGL(k_g2,  dim3(704),    dim3(256), 0, stream, past, inputs, b_out, b_qz,
                     interI, hypI, ws, outp);
}

// Round 4
// 570.868 us; speedup vs baseline: 1.0066x; 1.0066x over previous
//
#include <hip/hip_runtime.h>
#include <hip/hip_bf16.h>

// Problem constants
#define BB 4096
#define NNA 11
#define BN (BB*NNA)      // 45056

// ws float offsets (f32 scratch unless noted)
#define OFF_WEFF   0         // [4][256]
#define OFF_BIASL  1024      // [12][256]
#define OFF_WBIG   4096      // [48][256]
#define OFF_WALL   16640     // [48][256]
#define OFF_WG1F   31744     // [48][1152]
#define OFF_BIASG1 87040     // [11][1152]
#define OFF_WG2    99712     // bf16 WT[128][1536] (transposed tail weight), 98304 floats
#define OFF_WQT    198656    // bf16 WQT[64][128], 4096 floats
#define OFF_P2T    202752    // [12][256] per-l bias2 partials
#define OFF_P3T    205824    // [256] bias2@Wfc3_top
#define OFF_MIX    296320    // [4096][242]  attn(121)|A(121)
#define OFF_INTER  1287552   // bf16 region start (float-offset): inter[BN][256], hyp[BN][256]

typedef short bh8 __attribute__((ext_vector_type(8)));   // 8 bf16 (4 VGPRs) MFMA A/B frag
typedef float fx4 __attribute__((ext_vector_type(4)));   // MFMA C/D frag

__device__ __forceinline__ short f2bs(float v) { __hip_bfloat16 h = __float2bfloat16(v); return *(short*)&h; }

// ---------- Prologue: weight folding (f32, K-split mini-GEMMs) ----------

// grid 4: C[16][256] = A[16][512] @ W_pos[512][256]
__global__ __launch_bounds__(256) void k_p1(const float* W_in, const float* b_in,
                                            const float* W_pos, const float* b_pos,
                                            float* ws) {
  __shared__ float A[16*512];
  __shared__ float red[4*16*64];
  int t = threadIdx.x, cb = blockIdx.x;
  int ks = t >> 6, c = t & 63, col = cb*64 + c;
  float coef = -logf(10000.f) / 256.f;
  for (int i = t; i < 16*512; i += 256) {
    int row = i >> 9, kk = i & 511;
    float v;
    if (row < 4) v = (kk < 256) ? W_in[row*256 + kk] : 0.f;
    else if (kk < 256) v = b_in[kk];
    else {
      int ii = (kk - 256) >> 1;
      float dv = expf(coef * (float)(2*ii));
      float ang = (float)(row - 4) * dv;
      v = (kk & 1) ? cosf(ang) : sinf(ang);
    }
    A[i] = v;
  }
  __syncthreads();
  float acc[16];
  #pragma unroll
  for (int r = 0; r < 16; ++r) acc[r] = 0.f;
  #pragma unroll 4
  for (int j = 0; j < 128; ++j) {
    int jj = ks*128 + j;
    float b = W_pos[(size_t)jj*256 + col];
    #pragma unroll
    for (int r = 0; r < 16; ++r) acc[r] += A[r*512 + jj] * b;
  }
  #pragma unroll
  for (int r = 0; r < 16; ++r) red[(ks*16 + r)*64 + c] = acc[r];
  __syncthreads();
  for (int i = t; i < 16*64; i += 256) {
    int row = i >> 6, cc = i & 63;
    float s = red[row*64+cc] + red[(16+row)*64+cc] + red[(32+row)*64+cc] + red[(48+row)*64+cc];
    int gcol = cb*64 + cc;
    if (row < 4) ws[OFF_WEFF + row*256 + gcol] = s;
    else         ws[OFF_BIASL + (row-4)*256 + gcol] = s + b_pos[gcol];
  }
}

// grid (4,12): per l, C[5][256] = A_l[5][256] @ W_fc2_l ; rows 0..3 -> W_big[l*4+c], row 4 -> P2T[l]
__global__ __launch_bounds__(256) void k_p2(const float* W_fc2, float* ws) {
  __shared__ float A[5*256];
  __shared__ float red[4*5*64];
  int t = threadIdx.x, cb = blockIdx.x, l = blockIdx.y;
  int ks = t >> 6, c = t & 63, col = cb*64 + c;
  for (int i = t; i < 5*256; i += 256) {
    int row = i >> 8, kk = i & 255;
    A[i] = (row < 4) ? ws[OFF_WEFF + row*256 + kk] : ws[OFF_BIASL + l*256 + kk];
  }
  __syncthreads();
  float acc[5] = {0.f, 0.f, 0.f, 0.f, 0.f};
  #pragma unroll 4
  for (int j = 0; j < 64; ++j) {
    int jj = ks*64 + j;
    float b = W_fc2[(size_t)(l*256 + jj)*256 + col];
    #pragma unroll
    for (int r = 0; r < 5; ++r) acc[r] += A[r*256 + jj] * b;
  }
  #pragma unroll
  for (int r = 0; r < 5; ++r) red[(ks*5 + r)*64 + c] = acc[r];
  __syncthreads();
  for (int i = t; i < 5*64; i += 256) {
    int row = i / 64, cc = i % 64;
    float s = red[row*64+cc] + red[(5+row)*64+cc] + red[(10+row)*64+cc] + red[(15+row)*64+cc];
    int gcol = cb*64 + cc;
    if (row < 4) ws[OFF_WBIG + (l*4 + row)*256 + gcol] = s;
    else         ws[OFF_P2T + l*256 + gcol] = s;
  }
}

// grid (4,7): C[49][256] = A[49][256] @ W_fc3_top ; rows 0..47 -> W_all, row 48 -> P3T
// bias2 (= b_fc2 + sum_l P2T[l]) inlined
__global__ __launch_bounds__(256) void k_p3(const float* W_fc3, const float* b_fc2, float* ws) {
  __shared__ float A[7*256];
  __shared__ float red[4*7*64];
  int t = threadIdx.x, cb = blockIdx.x, rg = blockIdx.y;
  int ks = t >> 6, c = t & 63, col = cb*64 + c;
  for (int i = t; i < 7*256; i += 256) {
    int row = i >> 8, kk = i & 255, gr = rg*7 + row;
    float v;
    if (gr < 48) v = ws[OFF_WBIG + gr*256 + kk];
    else {
      v = b_fc2[kk];
      #pragma unroll
      for (int l = 0; l < 12; ++l) v += ws[OFF_P2T + l*256 + kk];
    }
    A[i] = v;
  }
  __syncthreads();
  float acc[7] = {0.f,0.f,0.f,0.f,0.f,0.f,0.f};
  #pragma unroll 4
  for (int j = 0; j < 64; ++j) {
    int jj = ks*64 + j;
    float b = W_fc3[(size_t)jj*256 + col];
    #pragma unroll
    for (int r = 0; r < 7; ++r) acc[r] += A[r*256 + jj] * b;
  }
  #pragma unroll
  for (int r = 0; r < 7; ++r) red[(ks*7 + r)*64 + c] = acc[r];
  __syncthreads();
  for (int i = t; i < 7*64; i += 256) {
    int row = i / 64, cc = i % 64, gr = rg*7 + row;
    float s = red[row*64+cc] + red[(7+row)*64+cc] + red[(14+row)*64+cc] + red[(21+row)*64+cc];
    int gcol = cb*64 + cc;
    if (gr < 48)       ws[OFF_WALL + gr*256 + gcol] = s;
    else if (gr == 48) ws[OFF_P3T + gcol] = s;
  }
}

// Wg1 column map: [Wm_top|Wm_bot|Wh_top|Wh_bot|Wo_ftraj] (1152 cols)
__device__ __forceinline__ float wg1_elem(int j, int col, const float* W_msg,
                                          const float* W_hyp, const float* W_out) {
  if (col < 256)       return W_msg[j*256 + col];
  else if (col < 512)  return W_msg[(256+j)*256 + (col-256)];
  else if (col < 768)  return W_hyp[j*256 + (col-512)];
  else if (col < 1024) return W_hyp[(256+j)*256 + (col-768)];
  else                 return W_out[(960+j)*128 + (col-1024)];
}

// grid (18,8): C[59][1152] = A[59][256] @ Wg1 ; rows 0..47 -> Wg1f, 48..58 -> biasg1 (+b_msg/b_hyp)
// biasN (= P3T + b_fc3 + W_fc3[256+n]) inlined
__global__ __launch_bounds__(256) void k_p4(const float* W_msg, const float* b_msg,
                                            const float* W_hyp, const float* b_hyp,
                                            const float* W_out, const float* W_fc3,
                                            const float* b_fc3, float* ws) {
  __shared__ float A[8*256];
  __shared__ float red[4*8*64];
  int t = threadIdx.x, cb = blockIdx.x, rg = blockIdx.y;
  int ks = t >> 6, c = t & 63, col = cb*64 + c;
  for (int i = t; i < 8*256; i += 256) {
    int row = i >> 8, kk = i & 255, gr = rg*8 + row;
    float v;
    if (gr < 48)      v = ws[OFF_WALL + gr*256 + kk];
    else if (gr < 59) v = ws[OFF_P3T + kk] + b_fc3[kk] + W_fc3[(size_t)(256 + gr - 48)*256 + kk];
    else              v = 0.f;
    A[i] = v;
  }
  __syncthreads();
  float acc[8];
  #pragma unroll
  for (int r = 0; r < 8; ++r) acc[r] = 0.f;
  #pragma unroll 4
  for (int j = 0; j < 64; ++j) {
    int jj = ks*64 + j;
    float b = wg1_elem(jj, col, W_msg, W_hyp, W_out);
    #pragma unroll
    for (int r = 0; r < 8; ++r) acc[r] += A[r*256 + jj] * b;
  }
  #pragma unroll
  for (int r = 0; r < 8; ++r) red[(ks*8 + r)*64 + c] = acc[r];
  __syncthreads();
  for (int i = t; i < 8*64; i += 256) {
    int row = i >> 6, cc = i & 63, gr = rg*8 + row;
    float s = red[row*64+cc] + red[(8+row)*64+cc] + red[(16+row)*64+cc] + red[(24+row)*64+cc];
    int gcol = cb*64 + cc;
    if (gr < 48) {
      ws[OFF_WG1F + gr*1152 + gcol] = s;
    } else if (gr < 59) {
      if (gcol < 256) s += b_msg[gcol];
      else if (gcol >= 512 && gcol < 768) s += b_hyp[gcol-512];
      ws[OFF_BIASG1 + (gr-48)*1152 + gcol] = s;
    }
  }
}

// grid 1600, block 128: blocks 0..1535: WT[c][r] (bf16, transposed); blocks 1536..1599: WQT
__global__ __launch_bounds__(128) void k_p5(const float* W_line, const float* W_out,
                                            const float* W_qz, float* ws) {
  int t = threadIdx.x;
  if (blockIdx.x >= 1536) {
    int i = (blockIdx.x - 1536)*128 + t;   // 0..8191
    int n = i >> 7, k = i & 127;
    short* WQs = (short*)(ws + OFF_WQT);
    WQs[n*128 + k] = f2bs(W_qz[k*64 + n]);
    return;
  }
  int c = t, r = blockIdx.x;
  float v;
  if (r < 960)       v = W_out[r*128 + c];
  else if (r < 1216) v = W_out[(r+256)*128 + c];
  else if (r < 1472) {
    int dd = r - 1216;
    float s = 0.f;
    for (int j = 0; j < 64; ++j)
      s += W_line[dd*64 + j] * W_out[(1472+j)*128 + c];
    v = s;
  } else if (r < 1520) {
    v = ws[OFF_WG1F + (r-1472)*1152 + 1024 + c];
  } else v = 0.f;
  short* WTs = (short*)(ws + OFF_WG2);
  WTs[(size_t)c*1536 + r] = f2bs(v);
}

// ---------- Front: ftraj GEMM (K=48) + per-scene corr -> attn/A ----------
// X values are wave-uniform (indices = blockIdx + loop constants): read them
// directly from global as scalar loads (__restrict__ enables SMEM/s_load path).
// No XT LDS staging -> LDS unit freed, occupancy up. FMA order unchanged ->
// bit-identical output.
__global__ __launch_bounds__(256) void k_front(const float* __restrict__ inputs,
                                               const float* __restrict__ W_fc3,
                                               const float* __restrict__ b_fc3,
                                               float* __restrict__ ws) {
  __shared__ float F[44*260];
  __shared__ float C[4*121];
  int t = threadIdx.x;
  int R0 = blockIdx.x * 44;
  { // ftraj = X48 @ W_all + bias_n (biasN inlined: P3T + b_fc3 + W_fc3 row)
    int d = t;
    float acc[44];
    float base = ws[OFF_P3T + d] + b_fc3[d];
    #pragma unroll
    for (int r = 0; r < 44; ++r) acc[r] = base + W_fc3[(size_t)(256 + (r % 11))*256 + d];
    for (int k = 0; k < 48; ++k) {
      float w = ws[OFF_WALL + k*256 + d];
      #pragma unroll
      for (int r = 0; r < 44; ++r)
        acc[r] += inputs[(size_t)(R0 + r)*48 + k] * w;
    }
    #pragma unroll
    for (int r = 0; r < 44; ++r) F[r*260 + d] = acc[r];
  }
  __syncthreads();
  int w = t >> 6, lane = t & 63;
  { // gram: 66 unique pairs per scene, one wave per scene
    const float4* F4 = (const float4*)F;   // row stride 65 float4s
    for (int p = lane; p < 66; p += 64) {
      int n = 0, pp = p;
      while (pp >= 11 - n) { pp -= 11 - n; ++n; }
      int m = n + pp;
      int ra = (w*11 + n) * 65, rb2 = (w*11 + m) * 65;
      float s = 0.f;
      #pragma unroll 4
      for (int j = 0; j < 64; ++j) {
        float4 a = F4[ra + j], b = F4[rb2 + j];
        s += a.x*b.x + a.y*b.y + a.z*b.z + a.w*b.w;
      }
      C[w*121 + n*11 + m] = s;
      C[w*121 + m*11 + n] = s;
    }
  }
  __syncthreads();
  { // attn (softmax of C/16) and A (thresholded, degree-normalized)
    float* Cw = C + w*121;
    float rn[11];
    #pragma unroll
    for (int n = 0; n < 11; ++n) rn[n] = 1.f / sqrtf(Cw[n*11+n]);
    float a = 1e30f;
    for (int n = 0; n < 11; ++n)
      for (int m = 0; m < 11; ++m)
        a = fminf(a, Cw[n*11+m] * rn[n] * rn[m]);
    float thr = (a < 0.4f) ? 0.4f : (((a > 0.4f) && (a < 0.6f)) ? a + 0.1f : a + 0.03f);
    int scene = blockIdx.x*4 + w;
    float* mixb = ws + OFF_MIX + (size_t)scene*242;
    if (lane < 11) {
      int n = lane;
      float mx = -1e30f;
      #pragma unroll
      for (int m = 0; m < 11; ++m) mx = fmaxf(mx, Cw[n*11+m]);
      mx *= (1.f/16.f);
      float e[11], ssum = 0.f;
      #pragma unroll
      for (int m = 0; m < 11; ++m) { e[m] = expf(Cw[n*11+m]*(1.f/16.f) - mx); ssum += e[m]; }
      float inv = 1.f / ssum;
      #pragma unroll
      for (int m = 0; m < 11; ++m) mixb[n*11+m] = e[m]*inv;
      float keep[11], cnt = 0.f;
      #pragma unroll
      for (int m = 0; m < 11; ++m) {
        float q = Cw[n*11+m] * rn[n] * rn[m];
        keep[m] = (q >= thr) ? 1.f : 0.f; cnt += keep[m];
      }
      float sc = 1.f / fmaxf(cnt, 1.f);
      #pragma unroll
      for (int m = 0; m < 11; ++m) mixb[121 + n*11 + m] = keep[m]*sc;
    }
  }
}

// ---------- Mix: P = X48 @ Wg1f (+bias), register attn/A mixing, relu -> inter/hyp (bf16) ----------
// Zero LDS, zero barriers: X and MW are wave-uniform -> scalar loads (SMEM);
// only the weight/bias loads are per-lane vector loads. FMA order identical to
// the staged version -> bit-identical output.
__global__ __launch_bounds__(256) void k_mix(const float* __restrict__ inputs,
                                             const float* __restrict__ ws,
                                             __hip_bfloat16* __restrict__ outI,
                                             __hip_bfloat16* __restrict__ outH) {
  int t = threadIdx.x;
  int s0 = blockIdx.x * 2;
  int R0 = s0 * 11;
  int gy = blockIdx.y;
  __hip_bfloat16* dst = gy ? outH : outI;
  int gc = gy*512 + t;           // top col; bot col = gc+256
  float accT[22], accB[22];
  #pragma unroll
  for (int r = 0; r < 22; ++r) {
    accT[r] = ws[OFF_BIASG1 + (r % 11)*1152 + gc];
    accB[r] = ws[OFF_BIASG1 + (r % 11)*1152 + gc + 256];
  }
  for (int k = 0; k < 48; ++k) {
    float wt = ws[OFF_WG1F + k*1152 + gc];
    float wb = ws[OFF_WG1F + k*1152 + gc + 256];
    #pragma unroll
    for (int r = 0; r < 22; ++r) {
      float xv = inputs[(size_t)(R0 + r)*48 + k];   // wave-uniform -> s_load
      accT[r] += xv * wt;
      accB[r] += xv * wb;
    }
  }
  #pragma unroll
  for (int s = 0; s < 2; ++s)
    #pragma unroll
    for (int n = 0; n < 11; ++n) {
      float v = accT[s*11+n];
      #pragma unroll
      for (int m = 0; m < 11; ++m)
        v += ws[OFF_MIX + (size_t)(s0+s)*242 + gy*121 + n*11 + m] * accB[s*11+m];  // uniform -> s_load
      v = fmaxf(v, 0.f);
      dst[(size_t)(R0 + s*11 + n)*256 + t] = __float2bfloat16(v);
    }
}

// ---------- Tail: bf16 MFMA GEMM (baseline structure, known-good ~<100us) ----------
// grid 704, block 256 (4 waves). Tile M=64 x N=128, K=1536 in 24 chunks of 64.
// LDS (shorts): A[64][72] @0 (4608) | BT[128][72] @4608 (9216) ; epilogue: hs[64][136] @0 | WQ[64][136] @8704.
#define A_OFF 0
#define BT_OFF 4608
#define HS_OFF 0
#define WQ_OFF 8704
__global__ __launch_bounds__(256) void k_g2(const float* past, const float* inputs,
                                            const float* b_out, const float* b_qz,
                                            const __hip_bfloat16* interI, const __hip_bfloat16* hypI,
                                            float* ws, float* out) {
  __shared__ short LDS[18432];   // 36 KB
  int t = threadIdx.x;
  int R0 = blockIdx.x * 64;
  int w = t >> 6, lane = t & 63, quad = lane >> 4, l16 = lane & 15;
  const short* WTs = (const short*)(ws + OFF_WG2);
  const short* WQs = (const short*)(ws + OFF_WQT);
  const short* intS = (const short*)interI;
  const short* hypS = (const short*)hypI;

  // acc init: b_out[col] + biasg1_tail[row%11][col]
  fx4 acc[4][2];
  #pragma unroll
  for (int mt = 0; mt < 4; ++mt)
    #pragma unroll
    for (int reg = 0; reg < 4; ++reg) {
      int nidx = (R0 + mt*16 + quad*4 + reg) % 11;
      #pragma unroll
      for (int nt = 0; nt < 2; ++nt) {
        int col = w*32 + nt*16 + l16;
        acc[mt][nt][reg] = b_out[col] + ws[OFF_BIASG1 + nidx*1152 + 1024 + col];
      }
    }

  int ar = t >> 2, akq = (t & 3) * 16;   // A-stage: row, k-quarter
  int bn = t >> 1, bkh = (t & 1) * 32;   // B-stage: n-row, k-half
  for (int ch = 0; ch < 24; ++ch) {
    __syncthreads();
    { // stage A chunk (64 rows x 64 k) as bf16
      short tmp[16];
      if (ch < 15) {
        const float4* sp = (const float4*)(past + (size_t)(R0+ar)*960 + ch*64 + akq);
        #pragma unroll
        for (int q = 0; q < 4; ++q) {
          float4 v = sp[q];
          tmp[4*q+0]=f2bs(v.x); tmp[4*q+1]=f2bs(v.y); tmp[4*q+2]=f2bs(v.z); tmp[4*q+3]=f2bs(v.w);
        }
        *(bh8*)&LDS[A_OFF + ar*72 + akq]     = *(bh8*)&tmp[0];
        *(bh8*)&LDS[A_OFF + ar*72 + akq + 8] = *(bh8*)&tmp[8];
      } else if (ch < 23) {
        const short* s = ((ch < 19) ? intS : hypS) + (size_t)(R0+ar)*256 + ((ch < 19) ? (ch-15) : (ch-19))*64 + akq;
        *(bh8*)&LDS[A_OFF + ar*72 + akq]     = *(const bh8*)&s[0];
        *(bh8*)&LDS[A_OFF + ar*72 + akq + 8] = *(const bh8*)&s[8];
      } else {
        if (akq < 48) {
          const float4* sp = (const float4*)(inputs + (size_t)(R0+ar)*48 + akq);
          #pragma unroll
          for (int q = 0; q < 4; ++q) {
            float4 v = sp[q];
            tmp[4*q+0]=f2bs(v.x); tmp[4*q+1]=f2bs(v.y); tmp[4*q+2]=f2bs(v.z); tmp[4*q+3]=f2bs(v.w);
          }
        } else {
          #pragma unroll
          for (int q = 0; q < 16; ++q) tmp[q] = 0;
        }
        *(bh8*)&LDS[A_OFF + ar*72 + akq]     = *(bh8*)&tmp[0];
        *(bh8*)&LDS[A_OFF + ar*72 + akq + 8] = *(bh8*)&tmp[8];
      }
    }
    { // stage BT chunk (128 n x 64 k)
      const short* s = WTs + (size_t)bn*1536 + ch*64 + bkh;
      #pragma unroll
      for (int q = 0; q < 4; ++q)
        *(bh8*)&LDS[BT_OFF + bn*72 + bkh + q*8] = *(const bh8*)&s[q*8];
    }
    __syncthreads();
    #pragma unroll
    for (int ks = 0; ks < 2; ++ks) {
      int kk = ks*32 + quad*8;
      bh8 a[4], b[2];
      #pragma unroll
      for (int mt = 0; mt < 4; ++mt) a[mt] = *(const bh8*)&LDS[A_OFF + (mt*16 + l16)*72 + kk];
      #pragma unroll
      for (int nt = 0; nt < 2; ++nt) b[nt] = *(const bh8*)&LDS[BT_OFF + (w*32 + nt*16 + l16)*72 + kk];
      #pragma unroll
      for (int mt = 0; mt < 4; ++mt)
        #pragma unroll
        for (int nt = 0; nt < 2; ++nt)
          acc[mt][nt] = __builtin_amdgcn_mfma_f32_16x16x32_bf16(a[mt], b[nt], acc[mt][nt], 0, 0, 0);
    }
  }
  __syncthreads();
  // hs = relu(acc) as bf16 into LDS (C layout: row = quad*4+reg, col = l16 within tiles)
  #pragma unroll
  for (int mt = 0; mt < 4; ++mt)
    #pragma unroll
    for (int nt = 0; nt < 2; ++nt)
      #pragma unroll
      for (int reg = 0; reg < 4; ++reg)
        LDS[HS_OFF + (mt*16 + quad*4 + reg)*136 + w*32 + nt*16 + l16] = f2bs(fmaxf(acc[mt][nt][reg], 0.f));
  { // stage WQT (64 n x 128 k)
    int n = t >> 2, kh = (t & 3) * 32;
    const short* s = WQs + n*128 + kh;
    #pragma unroll
    for (int q = 0; q < 4; ++q)
      *(bh8*)&LDS[WQ_OFF + n*136 + kh + q*8] = *(const bh8*)&s[q*8];
  }
  __syncthreads();
  // out = h @ W_qz + b_qz : M=64, N=64 (16/wave), K=128
  fx4 acc2[4];
  {
    float bq = b_qz[w*16 + l16];
    #pragma unroll
    for (int mt = 0; mt < 4; ++mt) { acc2[mt][0]=bq; acc2[mt][1]=bq; acc2[mt][2]=bq; acc2[mt][3]=bq; }
  }
  #pragma unroll
  for (int ks = 0; ks < 4; ++ks) {
    int kk = ks*32 + quad*8;
    bh8 bb = *(const bh8*)&LDS[WQ_OFF + (w*16 + l16)*136 + kk];
    #pragma unroll
    for (int mt = 0; mt < 4; ++mt) {
      bh8 aa = *(const bh8*)&LDS[HS_OFF + (mt*16 + l16)*136 + kk];
      acc2[mt] = __builtin_amdgcn_mfma_f32_16x16x32_bf16(aa, bb, acc2[mt], 0, 0, 0);
    }
  }
  #pragma unroll
  for (int mt = 0; mt < 4; ++mt)
    #pragma unroll
    for (int reg = 0; reg < 4; ++reg)
      out[(size_t)(R0 + mt*16 + quad*4 + reg)*64 + w*16 + l16] = acc2[mt][reg];
}

extern "C" void kernel_launch(void* const* d_in, const int* in_sizes, int n_in,
                              void* d_out, int out_size, void* d_ws, size_t ws_size,
                              hipStream_t stream) {
  const float* inputs = (const float*)d_in[0];
  const float* past   = (const float*)d_in[1];
  const float* W_in   = (const float*)d_in[2];
  const float* b_in   = (const float*)d_in[3];
  const float* W_pos  = (const float*)d_in[4];
  const float* b_pos  = (const float*)d_in[5];
  const float* W_fc2  = (const float*)d_in[6];
  const float* b_fc2  = (const float*)d_in[7];
  const float* W_fc3  = (const float*)d_in[8];
  const float* b_fc3  = (const float*)d_in[9];
  const float* W_msg  = (const float*)d_in[10];
  const float* b_msg  = (const float*)d_in[11];
  const float* W_hyp  = (const float*)d_in[12];
  const float* b_hyp  = (const float*)d_in[13];
  const float* W_line = (const float*)d_in[14];
  const float* W_out  = (const float*)d_in[15];
  const float* b_out  = (const float*)d_in[16];
  const float* W_qz   = (const float*)d_in[17];
  const float* b_qz   = (const float*)d_in[18];
  float* ws = (float*)d_ws;
  __hip_bfloat16* interI = (__hip_bfloat16*)(ws + OFF_INTER);
  __hip_bfloat16* hypI   = interI + (size_t)BN*256;
  float* outp   = (float*)d_out;

  hipLaunchKernelGGL(k_p1,  dim3(4),      dim3(256), 0, stream, W_in, b_in, W_pos, b_pos, ws);
  hipLaunchKernelGGL(k_p2,  dim3(4, 12),  dim3(256), 0, stream, W_fc2, ws);
  hipLaunchKernelGGL(k_p3,  dim3(4, 7),   dim3(256), 0, stream, W_fc3, b_fc2, ws);
  hipLaunchKernelGGL(k_p4,  dim3(18, 8),  dim3(256), 0, stream, W_msg, b_msg, W_hyp, b_hyp, W_out, W_fc3, b_fc3, ws);
  hipLaunchKernelGGL(k_p5,  dim3(1600),   dim3(128), 0, stream, W_line, W_out, W_qz, ws);
  hipLaunchKernelGGL(k_front, dim3(1024), dim3(256), 0, stream, inputs, W_fc3, b_fc3, ws);
  hipLaunchKernelGGL(k_mix, dim3(2048, 2), dim3(256), 0, stream, inputs, ws, interI, hypI);
  hipLaunchKernelGGL(k_g2,  dim3(704),    dim3(256), 0, stream, past, inputs, b_out, b_qz,
                     interI, hypI, ws, outp);
}

// Round 5
// 495.991 us; speedup vs baseline: 1.1585x; 1.1510x over previous
//
#include <hip/hip_runtime.h>
#include <hip/hip_bf16.h>

// Problem constants
#define BB 4096
#define NNA 11
#define BN (BB*NNA)      // 45056

// ws float offsets (f32 scratch unless noted)
#define OFF_WEFF   0         // [4][256]
#define OFF_BIASL  1024      // [12][256]
#define OFF_WBIG   4096      // [48][256]
#define OFF_WALL   16640     // [48][256]
#define OFF_WG1F   31744     // [48][1152]
#define OFF_BIASG1 87040     // [11][1152]
#define OFF_WG2    99712     // bf16 WT[128][1536] (transposed tail weight), 98304 floats
#define OFF_WQT    198656    // bf16 WQT[64][128], 4096 floats
#define OFF_P2T    202752    // [12][256] per-l bias2 partials
#define OFF_P3T    205824    // [256] bias2@Wfc3_top
#define OFF_MIX    296320    // [4096][242]  attn(121)|A(121)
#define OFF_INTER  1287552   // bf16 region start (float-offset): inter[BN][256], hyp[BN][256]

typedef short bh8 __attribute__((ext_vector_type(8)));   // 8 bf16 (4 VGPRs) MFMA A/B frag
typedef float fx4 __attribute__((ext_vector_type(4)));   // MFMA C/D frag

__device__ __forceinline__ short f2bs(float v) { __hip_bfloat16 h = __float2bfloat16(v); return *(short*)&h; }

// ---------- Prologue: weight folding (f32, K-split mini-GEMMs) ----------

// grid 4: C[16][256] = A[16][512] @ W_pos[512][256]
__global__ __launch_bounds__(256) void k_p1(const float* W_in, const float* b_in,
                                            const float* W_pos, const float* b_pos,
                                            float* ws) {
  __shared__ float A[16*512];
  __shared__ float red[4*16*64];
  int t = threadIdx.x, cb = blockIdx.x;
  int ks = t >> 6, c = t & 63, col = cb*64 + c;
  float coef = -logf(10000.f) / 256.f;
  for (int i = t; i < 16*512; i += 256) {
    int row = i >> 9, kk = i & 511;
    float v;
    if (row < 4) v = (kk < 256) ? W_in[row*256 + kk] : 0.f;
    else if (kk < 256) v = b_in[kk];
    else {
      int ii = (kk - 256) >> 1;
      float dv = expf(coef * (float)(2*ii));
      float ang = (float)(row - 4) * dv;
      v = (kk & 1) ? cosf(ang) : sinf(ang);
    }
    A[i] = v;
  }
  __syncthreads();
  float acc[16];
  #pragma unroll
  for (int r = 0; r < 16; ++r) acc[r] = 0.f;
  #pragma unroll 4
  for (int j = 0; j < 128; ++j) {
    int jj = ks*128 + j;
    float b = W_pos[(size_t)jj*256 + col];
    #pragma unroll
    for (int r = 0; r < 16; ++r) acc[r] += A[r*512 + jj] * b;
  }
  #pragma unroll
  for (int r = 0; r < 16; ++r) red[(ks*16 + r)*64 + c] = acc[r];
  __syncthreads();
  for (int i = t; i < 16*64; i += 256) {
    int row = i >> 6, cc = i & 63;
    float s = red[row*64+cc] + red[(16+row)*64+cc] + red[(32+row)*64+cc] + red[(48+row)*64+cc];
    int gcol = cb*64 + cc;
    if (row < 4) ws[OFF_WEFF + row*256 + gcol] = s;
    else         ws[OFF_BIASL + (row-4)*256 + gcol] = s + b_pos[gcol];
  }
}

// grid (4,12): per l, C[5][256] = A_l[5][256] @ W_fc2_l ; rows 0..3 -> W_big[l*4+c], row 4 -> P2T[l]
__global__ __launch_bounds__(256) void k_p2(const float* W_fc2, float* ws) {
  __shared__ float A[5*256];
  __shared__ float red[4*5*64];
  int t = threadIdx.x, cb = blockIdx.x, l = blockIdx.y;
  int ks = t >> 6, c = t & 63, col = cb*64 + c;
  for (int i = t; i < 5*256; i += 256) {
    int row = i >> 8, kk = i & 255;
    A[i] = (row < 4) ? ws[OFF_WEFF + row*256 + kk] : ws[OFF_BIASL + l*256 + kk];
  }
  __syncthreads();
  float acc[5] = {0.f, 0.f, 0.f, 0.f, 0.f};
  #pragma unroll 4
  for (int j = 0; j < 64; ++j) {
    int jj = ks*64 + j;
    float b = W_fc2[(size_t)(l*256 + jj)*256 + col];
    #pragma unroll
    for (int r = 0; r < 5; ++r) acc[r] += A[r*256 + jj] * b;
  }
  #pragma unroll
  for (int r = 0; r < 5; ++r) red[(ks*5 + r)*64 + c] = acc[r];
  __syncthreads();
  for (int i = t; i < 5*64; i += 256) {
    int row = i / 64, cc = i % 64;
    float s = red[row*64+cc] + red[(5+row)*64+cc] + red[(10+row)*64+cc] + red[(15+row)*64+cc];
    int gcol = cb*64 + cc;
    if (row < 4) ws[OFF_WBIG + (l*4 + row)*256 + gcol] = s;
    else         ws[OFF_P2T + l*256 + gcol] = s;
  }
}

// grid (4,7): C[49][256] = A[49][256] @ W_fc3_top ; rows 0..47 -> W_all, row 48 -> P3T
// bias2 (= b_fc2 + sum_l P2T[l]) inlined
__global__ __launch_bounds__(256) void k_p3(const float* W_fc3, const float* b_fc2, float* ws) {
  __shared__ float A[7*256];
  __shared__ float red[4*7*64];
  int t = threadIdx.x, cb = blockIdx.x, rg = blockIdx.y;
  int ks = t >> 6, c = t & 63, col = cb*64 + c;
  for (int i = t; i < 7*256; i += 256) {
    int row = i >> 8, kk = i & 255, gr = rg*7 + row;
    float v;
    if (gr < 48) v = ws[OFF_WBIG + gr*256 + kk];
    else {
      v = b_fc2[kk];
      #pragma unroll
      for (int l = 0; l < 12; ++l) v += ws[OFF_P2T + l*256 + kk];
    }
    A[i] = v;
  }
  __syncthreads();
  float acc[7] = {0.f,0.f,0.f,0.f,0.f,0.f,0.f};
  #pragma unroll 4
  for (int j = 0; j < 64; ++j) {
    int jj = ks*64 + j;
    float b = W_fc3[(size_t)jj*256 + col];
    #pragma unroll
    for (int r = 0; r < 7; ++r) acc[r] += A[r*256 + jj] * b;
  }
  #pragma unroll
  for (int r = 0; r < 7; ++r) red[(ks*7 + r)*64 + c] = acc[r];
  __syncthreads();
  for (int i = t; i < 7*64; i += 256) {
    int row = i / 64, cc = i % 64, gr = rg*7 + row;
    float s = red[row*64+cc] + red[(7+row)*64+cc] + red[(14+row)*64+cc] + red[(21+row)*64+cc];
    int gcol = cb*64 + cc;
    if (gr < 48)       ws[OFF_WALL + gr*256 + gcol] = s;
    else if (gr == 48) ws[OFF_P3T + gcol] = s;
  }
}

// Wg1 column map: [Wm_top|Wm_bot|Wh_top|Wh_bot|Wo_ftraj] (1152 cols)
__device__ __forceinline__ float wg1_elem(int j, int col, const float* W_msg,
                                          const float* W_hyp, const float* W_out) {
  if (col < 256)       return W_msg[j*256 + col];
  else if (col < 512)  return W_msg[(256+j)*256 + (col-256)];
  else if (col < 768)  return W_hyp[j*256 + (col-512)];
  else if (col < 1024) return W_hyp[(256+j)*256 + (col-768)];
  else                 return W_out[(960+j)*128 + (col-1024)];
}

// grid (18,8): C[59][1152] = A[59][256] @ Wg1 ; rows 0..47 -> Wg1f, 48..58 -> biasg1 (+b_msg/b_hyp)
// biasN (= P3T + b_fc3 + W_fc3[256+n]) inlined
__global__ __launch_bounds__(256) void k_p4(const float* W_msg, const float* b_msg,
                                            const float* W_hyp, const float* b_hyp,
                                            const float* W_out, const float* W_fc3,
                                            const float* b_fc3, float* ws) {
  __shared__ float A[8*256];
  __shared__ float red[4*8*64];
  int t = threadIdx.x, cb = blockIdx.x, rg = blockIdx.y;
  int ks = t >> 6, c = t & 63, col = cb*64 + c;
  for (int i = t; i < 8*256; i += 256) {
    int row = i >> 8, kk = i & 255, gr = rg*8 + row;
    float v;
    if (gr < 48)      v = ws[OFF_WALL + gr*256 + kk];
    else if (gr < 59) v = ws[OFF_P3T + kk] + b_fc3[kk] + W_fc3[(size_t)(256 + gr - 48)*256 + kk];
    else              v = 0.f;
    A[i] = v;
  }
  __syncthreads();
  float acc[8];
  #pragma unroll
  for (int r = 0; r < 8; ++r) acc[r] = 0.f;
  #pragma unroll 4
  for (int j = 0; j < 64; ++j) {
    int jj = ks*64 + j;
    float b = wg1_elem(jj, col, W_msg, W_hyp, W_out);
    #pragma unroll
    for (int r = 0; r < 8; ++r) acc[r] += A[r*256 + jj] * b;
  }
  #pragma unroll
  for (int r = 0; r < 8; ++r) red[(ks*8 + r)*64 + c] = acc[r];
  __syncthreads();
  for (int i = t; i < 8*64; i += 256) {
    int row = i >> 6, cc = i & 63, gr = rg*8 + row;
    float s = red[row*64+cc] + red[(8+row)*64+cc] + red[(16+row)*64+cc] + red[(24+row)*64+cc];
    int gcol = cb*64 + cc;
    if (gr < 48) {
      ws[OFF_WG1F + gr*1152 + gcol] = s;
    } else if (gr < 59) {
      if (gcol < 256) s += b_msg[gcol];
      else if (gcol >= 512 && gcol < 768) s += b_hyp[gcol-512];
      ws[OFF_BIASG1 + (gr-48)*1152 + gcol] = s;
    }
  }
}

// grid 1600, block 128: blocks 0..1535: WT[c][r] (bf16, transposed); blocks 1536..1599: WQT
__global__ __launch_bounds__(128) void k_p5(const float* W_line, const float* W_out,
                                            const float* W_qz, float* ws) {
  int t = threadIdx.x;
  if (blockIdx.x >= 1536) {
    int i = (blockIdx.x - 1536)*128 + t;   // 0..8191
    int n = i >> 7, k = i & 127;
    short* WQs = (short*)(ws + OFF_WQT);
    WQs[n*128 + k] = f2bs(W_qz[k*64 + n]);
    return;
  }
  int c = t, r = blockIdx.x;
  float v;
  if (r < 960)       v = W_out[r*128 + c];
  else if (r < 1216) v = W_out[(r+256)*128 + c];
  else if (r < 1472) {
    int dd = r - 1216;
    float s = 0.f;
    for (int j = 0; j < 64; ++j)
      s += W_line[dd*64 + j] * W_out[(1472+j)*128 + c];
    v = s;
  } else if (r < 1520) {
    v = ws[OFF_WG1F + (r-1472)*1152 + 1024 + c];
  } else v = 0.f;
  short* WTs = (short*)(ws + OFF_WG2);
  WTs[(size_t)c*1536 + r] = f2bs(v);
}

// ---------- Front: ftraj GEMM (K=48) + per-scene corr -> attn/A (baseline staged) ----------
__global__ __launch_bounds__(256) void k_front(const float* inputs, const float* W_fc3,
                                               const float* b_fc3, float* ws) {
  __shared__ float XT[48*44];
  __shared__ float F[44*260];
  __shared__ float C[4*121];
  int t = threadIdx.x;
  int R0 = blockIdx.x * 44;
  for (int i = t; i < 44*48; i += 256) {
    int r = i / 48, k = i - r*48;
    XT[k*44 + r] = inputs[(size_t)(R0+r)*48 + k];
  }
  __syncthreads();
  { // ftraj = X48 @ W_all + bias_n (biasN inlined: P3T + b_fc3 + W_fc3 row)
    int d = t;
    float acc[44];
    float base = ws[OFF_P3T + d] + b_fc3[d];
    #pragma unroll
    for (int r = 0; r < 44; ++r) acc[r] = base + W_fc3[(size_t)(256 + (r % 11))*256 + d];
    for (int k = 0; k < 48; ++k) {
      float w = ws[OFF_WALL + k*256 + d];
      #pragma unroll
      for (int j = 0; j < 11; ++j) {
        float4 xv = *(const float4*)&XT[k*44 + 4*j];
        acc[4*j+0] += xv.x*w; acc[4*j+1] += xv.y*w;
        acc[4*j+2] += xv.z*w; acc[4*j+3] += xv.w*w;
      }
    }
    #pragma unroll
    for (int r = 0; r < 44; ++r) F[r*260 + d] = acc[r];
  }
  __syncthreads();
  int w = t >> 6, lane = t & 63;
  { // gram: 66 unique pairs per scene, one wave per scene
    const float4* F4 = (const float4*)F;   // row stride 65 float4s
    for (int p = lane; p < 66; p += 64) {
      int n = 0, pp = p;
      while (pp >= 11 - n) { pp -= 11 - n; ++n; }
      int m = n + pp;
      int ra = (w*11 + n) * 65, rb2 = (w*11 + m) * 65;
      float s = 0.f;
      #pragma unroll 4
      for (int j = 0; j < 64; ++j) {
        float4 a = F4[ra + j], b = F4[rb2 + j];
        s += a.x*b.x + a.y*b.y + a.z*b.z + a.w*b.w;
      }
      C[w*121 + n*11 + m] = s;
      C[w*121 + m*11 + n] = s;
    }
  }
  __syncthreads();
  { // attn (softmax of C/16) and A (thresholded, degree-normalized)
    float* Cw = C + w*121;
    float rn[11];
    #pragma unroll
    for (int n = 0; n < 11; ++n) rn[n] = 1.f / sqrtf(Cw[n*11+n]);
    float a = 1e30f;
    for (int n = 0; n < 11; ++n)
      for (int m = 0; m < 11; ++m)
        a = fminf(a, Cw[n*11+m] * rn[n] * rn[m]);
    float thr = (a < 0.4f) ? 0.4f : (((a > 0.4f) && (a < 0.6f)) ? a + 0.1f : a + 0.03f);
    int scene = blockIdx.x*4 + w;
    float* mixb = ws + OFF_MIX + (size_t)scene*242;
    if (lane < 11) {
      int n = lane;
      float mx = -1e30f;
      #pragma unroll
      for (int m = 0; m < 11; ++m) mx = fmaxf(mx, Cw[n*11+m]);
      mx *= (1.f/16.f);
      float e[11], ssum = 0.f;
      #pragma unroll
      for (int m = 0; m < 11; ++m) { e[m] = expf(Cw[n*11+m]*(1.f/16.f) - mx); ssum += e[m]; }
      float inv = 1.f / ssum;
      #pragma unroll
      for (int m = 0; m < 11; ++m) mixb[n*11+m] = e[m]*inv;
      float keep[11], cnt = 0.f;
      #pragma unroll
      for (int m = 0; m < 11; ++m) {
        float q = Cw[n*11+m] * rn[n] * rn[m];
        keep[m] = (q >= thr) ? 1.f : 0.f; cnt += keep[m];
      }
      float sc = 1.f / fmaxf(cnt, 1.f);
      #pragma unroll
      for (int m = 0; m < 11; ++m) mixb[121 + n*11 + m] = keep[m]*sc;
    }
  }
}

// ---------- Mix: merged-gy. P = X48 @ Wg1f (+bias) for BOTH msg and hyp halves in one
// block, register attn/A mixing, relu -> inter & hyp (bf16). Rationale: baseline was
// LDS-issue-bound (6 ds_read_b128 broadcasts/k/wave; ~92us of b128 throughput chip-wide).
// Sharing each X broadcast across 4 accumulator sets (msgT/msgB/hypT/hypB) halves the
// ds_read count. FMA order per accumulator unchanged -> bit-identical output.
// grid 2048, block 256 (2 scenes per block). 96 f32 acc -> launch_bounds(256,2).
__global__ __launch_bounds__(256, 2) void k_mix(const float* inputs, float* ws,
                                             __hip_bfloat16* outI, __hip_bfloat16* outH) {
  __shared__ float XT[48*24];   // XT[k*24+r], rows 22,23 zero
  __shared__ float MW[4*121];   // [gy*2+s][121]
  int t = threadIdx.x;
  int s0 = blockIdx.x * 2;
  int R0 = s0 * 11;
  for (int i = t; i < 22*48; i += 256) {
    int r = i / 48, k = i - r*48;
    XT[k*24 + r] = inputs[(size_t)(R0+r)*48 + k];
  }
  for (int i = t; i < 96; i += 256) { int k = i >> 1, r = 22 + (i & 1); XT[k*24+r] = 0.f; }
  for (int i = t; i < 484; i += 256) {
    int gy = i / 242, j = i - gy*242;
    int s = j / 121, jj = j - s*121;
    MW[(gy*2 + s)*121 + jj] = ws[OFF_MIX + (size_t)(s0+s)*242 + gy*121 + jj];
  }
  __syncthreads();
  // 4 accumulator sets over 24 rows (22 live + 2 pad): msg top/bot, hyp top/bot
  float aT0[24], aB0[24], aT1[24], aB1[24];
  #pragma unroll
  for (int r = 0; r < 24; ++r) {
    if (r < 22) {
      int nb = OFF_BIASG1 + (r % 11)*1152 + t;
      aT0[r] = ws[nb];
      aB0[r] = ws[nb + 256];
      aT1[r] = ws[nb + 512];
      aB1[r] = ws[nb + 768];
    } else { aT0[r]=0.f; aB0[r]=0.f; aT1[r]=0.f; aB1[r]=0.f; }
  }
  for (int k = 0; k < 48; ++k) {
    float wt0 = ws[OFF_WG1F + k*1152 + t];
    float wb0 = ws[OFF_WG1F + k*1152 + t + 256];
    float wt1 = ws[OFF_WG1F + k*1152 + t + 512];
    float wb1 = ws[OFF_WG1F + k*1152 + t + 768];
    #pragma unroll
    for (int j = 0; j < 6; ++j) {
      float4 xv = *(const float4*)&XT[k*24 + 4*j];
      aT0[4*j+0] += xv.x*wt0; aT0[4*j+1] += xv.y*wt0; aT0[4*j+2] += xv.z*wt0; aT0[4*j+3] += xv.w*wt0;
      aB0[4*j+0] += xv.x*wb0; aB0[4*j+1] += xv.y*wb0; aB0[4*j+2] += xv.z*wb0; aB0[4*j+3] += xv.w*wb0;
      aT1[4*j+0] += xv.x*wt1; aT1[4*j+1] += xv.y*wt1; aT1[4*j+2] += xv.z*wt1; aT1[4*j+3] += xv.w*wt1;
      aB1[4*j+0] += xv.x*wb1; aB1[4*j+1] += xv.y*wb1; aB1[4*j+2] += xv.z*wb1; aB1[4*j+3] += xv.w*wb1;
    }
  }
  #pragma unroll
  for (int s = 0; s < 2; ++s)
    #pragma unroll
    for (int n = 0; n < 11; ++n) {
      float v0 = aT0[s*11+n];
      float v1 = aT1[s*11+n];
      #pragma unroll
      for (int m = 0; m < 11; ++m) {
        v0 += MW[s*121 + n*11 + m]       * aB0[s*11+m];
        v1 += MW[(2+s)*121 + n*11 + m]   * aB1[s*11+m];
      }
      outI[(size_t)(R0 + s*11 + n)*256 + t] = __float2bfloat16(fmaxf(v0, 0.f));
      outH[(size_t)(R0 + s*11 + n)*256 + t] = __float2bfloat16(fmaxf(v1, 0.f));
    }
}

// ---------- Tail: bf16 MFMA GEMM (baseline structure, known-good) ----------
// grid 704, block 256 (4 waves). Tile M=64 x N=128, K=1536 in 24 chunks of 64.
// LDS (shorts): A[64][72] @0 (4608) | BT[128][72] @4608 (9216) ; epilogue: hs[64][136] @0 | WQ[64][136] @8704.
#define A_OFF 0
#define BT_OFF 4608
#define HS_OFF 0
#define WQ_OFF 8704
__global__ __launch_bounds__(256) void k_g2(const float* past, const float* inputs,
                                            const float* b_out, const float* b_qz,
                                            const __hip_bfloat16* interI, const __hip_bfloat16* hypI,
                                            float* ws, float* out) {
  __shared__ short LDS[18432];   // 36 KB
  int t = threadIdx.x;
  int R0 = blockIdx.x * 64;
  int w = t >> 6, lane = t & 63, quad = lane >> 4, l16 = lane & 15;
  const short* WTs = (const short*)(ws + OFF_WG2);
  const short* WQs = (const short*)(ws + OFF_WQT);
  const short* intS = (const short*)interI;
  const short* hypS = (const short*)hypI;

  // acc init: b_out[col] + biasg1_tail[row%11][col]
  fx4 acc[4][2];
  #pragma unroll
  for (int mt = 0; mt < 4; ++mt)
    #pragma unroll
    for (int reg = 0; reg < 4; ++reg) {
      int nidx = (R0 + mt*16 + quad*4 + reg) % 11;
      #pragma unroll
      for (int nt = 0; nt < 2; ++nt) {
        int col = w*32 + nt*16 + l16;
        acc[mt][nt][reg] = b_out[col] + ws[OFF_BIASG1 + nidx*1152 + 1024 + col];
      }
    }

  int ar = t >> 2, akq = (t & 3) * 16;   // A-stage: row, k-quarter
  int bn = t >> 1, bkh = (t & 1) * 32;   // B-stage: n-row, k-half
  for (int ch = 0; ch < 24; ++ch) {
    __syncthreads();
    { // stage A chunk (64 rows x 64 k) as bf16
      short tmp[16];
      if (ch < 15) {
        const float4* sp = (const float4*)(past + (size_t)(R0+ar)*960 + ch*64 + akq);
        #pragma unroll
        for (int q = 0; q < 4; ++q) {
          float4 v = sp[q];
          tmp[4*q+0]=f2bs(v.x); tmp[4*q+1]=f2bs(v.y); tmp[4*q+2]=f2bs(v.z); tmp[4*q+3]=f2bs(v.w);
        }
        *(bh8*)&LDS[A_OFF + ar*72 + akq]     = *(bh8*)&tmp[0];
        *(bh8*)&LDS[A_OFF + ar*72 + akq + 8] = *(bh8*)&tmp[8];
      } else if (ch < 23) {
        const short* s = ((ch < 19) ? intS : hypS) + (size_t)(R0+ar)*256 + ((ch < 19) ? (ch-15) : (ch-19))*64 + akq;
        *(bh8*)&LDS[A_OFF + ar*72 + akq]     = *(const bh8*)&s[0];
        *(bh8*)&LDS[A_OFF + ar*72 + akq + 8] = *(const bh8*)&s[8];
      } else {
        if (akq < 48) {
          const float4* sp = (const float4*)(inputs + (size_t)(R0+ar)*48 + akq);
          #pragma unroll
          for (int q = 0; q < 4; ++q) {
            float4 v = sp[q];
            tmp[4*q+0]=f2bs(v.x); tmp[4*q+1]=f2bs(v.y); tmp[4*q+2]=f2bs(v.z); tmp[4*q+3]=f2bs(v.w);
          }
        } else {
          #pragma unroll
          for (int q = 0; q < 16; ++q) tmp[q] = 0;
        }
        *(bh8*)&LDS[A_OFF + ar*72 + akq]     = *(bh8*)&tmp[0];
        *(bh8*)&LDS[A_OFF + ar*72 + akq + 8] = *(bh8*)&tmp[8];
      }
    }
    { // stage BT chunk (128 n x 64 k)
      const short* s = WTs + (size_t)bn*1536 + ch*64 + bkh;
      #pragma unroll
      for (int q = 0; q < 4; ++q)
        *(bh8*)&LDS[BT_OFF + bn*72 + bkh + q*8] = *(const bh8*)&s[q*8];
    }
    __syncthreads();
    #pragma unroll
    for (int ks = 0; ks < 2; ++ks) {
      int kk = ks*32 + quad*8;
      bh8 a[4], b[2];
      #pragma unroll
      for (int mt = 0; mt < 4; ++mt) a[mt] = *(const bh8*)&LDS[A_OFF + (mt*16 + l16)*72 + kk];
      #pragma unroll
      for (int nt = 0; nt < 2; ++nt) b[nt] = *(const bh8*)&LDS[BT_OFF + (w*32 + nt*16 + l16)*72 + kk];
      #pragma unroll
      for (int mt = 0; mt < 4; ++mt)
        #pragma unroll
        for (int nt = 0; nt < 2; ++nt)
          acc[mt][nt] = __builtin_amdgcn_mfma_f32_16x16x32_bf16(a[mt], b[nt], acc[mt][nt], 0, 0, 0);
    }
  }
  __syncthreads();
  // hs = relu(acc) as bf16 into LDS (C layout: row = quad*4+reg, col = l16 within tiles)
  #pragma unroll
  for (int mt = 0; mt < 4; ++mt)
    #pragma unroll
    for (int nt = 0; nt < 2; ++nt)
      #pragma unroll
      for (int reg = 0; reg < 4; ++reg)
        LDS[HS_OFF + (mt*16 + quad*4 + reg)*136 + w*32 + nt*16 + l16] = f2bs(fmaxf(acc[mt][nt][reg], 0.f));
  { // stage WQT (64 n x 128 k)
    int n = t >> 2, kh = (t & 3) * 32;
    const short* s = WQs + n*128 + kh;
    #pragma unroll
    for (int q = 0; q < 4; ++q)
      *(bh8*)&LDS[WQ_OFF + n*136 + kh + q*8] = *(const bh8*)&s[q*8];
  }
  __syncthreads();
  // out = h @ W_qz + b_qz : M=64, N=64 (16/wave), K=128
  fx4 acc2[4];
  {
    float bq = b_qz[w*16 + l16];
    #pragma unroll
    for (int mt = 0; mt < 4; ++mt) { acc2[mt][0]=bq; acc2[mt][1]=bq; acc2[mt][2]=bq; acc2[mt][3]=bq; }
  }
  #pragma unroll
  for (int ks = 0; ks < 4; ++ks) {
    int kk = ks*32 + quad*8;
    bh8 bb = *(const bh8*)&LDS[WQ_OFF + (w*16 + l16)*136 + kk];
    #pragma unroll
    for (int mt = 0; mt < 4; ++mt) {
      bh8 aa = *(const bh8*)&LDS[HS_OFF + (mt*16 + l16)*136 + kk];
      acc2[mt] = __builtin_amdgcn_mfma_f32_16x16x32_bf16(aa, bb, acc2[mt], 0, 0, 0);
    }
  }
  #pragma unroll
  for (int mt = 0; mt < 4; ++mt)
    #pragma unroll
    for (int reg = 0; reg < 4; ++reg)
      out[(size_t)(R0 + mt*16 + quad*4 + reg)*64 + w*16 + l16] = acc2[mt][reg];
}

extern "C" void kernel_launch(void* const* d_in, const int* in_sizes, int n_in,
                              void* d_out, int out_size, void* d_ws, size_t ws_size,
                              hipStream_t stream) {
  const float* inputs = (const float*)d_in[0];
  const float* past   = (const float*)d_in[1];
  const float* W_in   = (const float*)d_in[2];
  const float* b_in   = (const float*)d_in[3];
  const float* W_pos  = (const float*)d_in[4];
  const float* b_pos  = (const float*)d_in[5];
  const float* W_fc2  = (const float*)d_in[6];
  const float* b_fc2  = (const float*)d_in[7];
  const float* W_fc3  = (const float*)d_in[8];
  const float* b_fc3  = (const float*)d_in[9];
  const float* W_msg  = (const float*)d_in[10];
  const float* b_msg  = (const float*)d_in[11];
  const float* W_hyp  = (const float*)d_in[12];
  const float* b_hyp  = (const float*)d_in[13];
  const float* W_line = (const float*)d_in[14];
  const float* W_out  = (const float*)d_in[15];
  const float* b_out  = (const float*)d_in[16];
  const float* W_qz   = (const float*)d_in[17];
  const float* b_qz   = (const float*)d_in[18];
  float* ws = (float*)d_ws;
  __hip_bfloat16* interI = (__hip_bfloat16*)(ws + OFF_INTER);
  __hip_bfloat16* hypI   = interI + (size_t)BN*256;
  float* outp   = (float*)d_out;

  hipLaunchKernelGGL(k_p1,  dim3(4),      dim3(256), 0, stream, W_in, b_in, W_pos, b_pos, ws);
  hipLaunchKernelGGL(k_p2,  dim3(4, 12),  dim3(256), 0, stream, W_fc2, ws);
  hipLaunchKernelGGL(k_p3,  dim3(4, 7),   dim3(256), 0, stream, W_fc3, b_fc2, ws);
  hipLaunchKernelGGL(k_p4,  dim3(18, 8),  dim3(256), 0, stream, W_msg, b_msg, W_hyp, b_hyp, W_out, W_fc3, b_fc3, ws);
  hipLaunchKernelGGL(k_p5,  dim3(1600),   dim3(128), 0, stream, W_line, W_out, W_qz, ws);
  hipLaunchKernelGGL(k_front, dim3(1024), dim3(256), 0, stream, inputs, W_fc3, b_fc3, ws);
  hipLaunchKernelGGL(k_mix, dim3(2048),   dim3(256), 0, stream, inputs, ws, interI, hypI);
  hipLaunchKernelGGL(k_g2,  dim3(704),    dim3(256), 0, stream, past, inputs, b_out, b_qz,
                     interI, hypI, ws, outp);
}